// Round 1
// baseline (641.104 us; speedup 1.0000x reference)
//
#include <hip/hip_runtime.h>
#include <hip/hip_bf16.h>
#include <stdint.h>

typedef uint16_t u16;
typedef __attribute__((ext_vector_type(8))) short bf16x8;
typedef __attribute__((ext_vector_type(4))) float f32x4;

#define DEVI static __device__ __forceinline__

constexpr int Bc = 4, Sc = 1024, Hc = 1024, NHc = 16, HDc = 64;
constexpr int Mrows = Bc * Sc; // 4096

DEVI u16 f2bf(float f) {
  uint32_t u = __builtin_bit_cast(uint32_t, f);
  u += 0x7FFFu + ((u >> 16) & 1u);
  return (u16)(u >> 16);
}

DEVI f32x4 mfma16(bf16x8 a, bf16x8 b, f32x4 c) {
  return __builtin_amdgcn_mfma_f32_16x16x32_bf16(a, b, c, 0, 0, 0);
}

// ---------------- f32 -> bf16 conversion ----------------
__global__ __launch_bounds__(256) void cvt_kernel(const float* __restrict__ in,
                                                  u16* __restrict__ out, int n8) {
  int i = blockIdx.x * 256 + threadIdx.x;
  if (i >= n8) return;
  const f32x4* p = (const f32x4*)(in + (size_t)i * 8);
  f32x4 a = p[0], b = p[1];
  union { bf16x8 v; u16 s[8]; } r;
#pragma unroll
  for (int j = 0; j < 4; ++j) { r.s[j] = f2bf(a[j]); r.s[4 + j] = f2bf(b[j]); }
  *(bf16x8*)(out + (size_t)i * 8) = r.v;
}

// ---------------- bf16 GEMM: C[M,N] = A[M,K] * Bw[N,K]^T + bias ----------------
// M=4096, N=K=1024. 128x128 tile, BK=32, 256 threads (4 waves, 2x2), 4x4 16x16 frags/wave.
// MODE 0: bf16 [M,N];  1: bf16 [b,h,s,d];  2: bf16 [b,h,d,s] (V transposed);  3: f32 [M,N]
template <int MODE>
__global__ __launch_bounds__(256) void gemm_bt(const u16* __restrict__ A,
                                               const u16* __restrict__ Bw,
                                               const float* __restrict__ bias,
                                               void* __restrict__ Cout) {
  constexpr int K = 1024, N = 1024, BK = 32;
  __shared__ u16 As[128 * BK];
  __shared__ u16 Bs[128 * BK];
  const int t = threadIdx.x;
  const int w = t >> 6, l = t & 63;
  const int lr = l & 15, lh = l >> 4;
  const int m0 = blockIdx.y * 128, n0 = blockIdx.x * 128;
  const int wr = w >> 1, wc = w & 1;
  f32x4 acc[4][4] = {};

  for (int kt = 0; kt < K; kt += BK) {
#pragma unroll
    for (int i = 0; i < 2; ++i) {
      int c = i * 256 + t;
      int row = c >> 2, k8 = (c & 3) << 3;
      *(bf16x8*)(As + (size_t)c * 8) = *(const bf16x8*)(A + (size_t)(m0 + row) * K + kt + k8);
      *(bf16x8*)(Bs + (size_t)c * 8) = *(const bf16x8*)(Bw + (size_t)(n0 + row) * K + kt + k8);
    }
    __syncthreads();
    bf16x8 af[4], bfr[4];
#pragma unroll
    for (int mi = 0; mi < 4; ++mi)
      af[mi] = *(const bf16x8*)(As + (wr * 64 + mi * 16 + lr) * BK + lh * 8);
#pragma unroll
    for (int ni = 0; ni < 4; ++ni)
      bfr[ni] = *(const bf16x8*)(Bs + (wc * 64 + ni * 16 + lr) * BK + lh * 8);
#pragma unroll
    for (int mi = 0; mi < 4; ++mi)
#pragma unroll
      for (int ni = 0; ni < 4; ++ni)
        acc[mi][ni] = mfma16(af[mi], bfr[ni], acc[mi][ni]);
    __syncthreads();
  }

#pragma unroll
  for (int mi = 0; mi < 4; ++mi) {
#pragma unroll
    for (int ni = 0; ni < 4; ++ni) {
      int col = n0 + wc * 64 + ni * 16 + lr;
      float bc = bias[col];
#pragma unroll
      for (int r = 0; r < 4; ++r) {
        int row = m0 + wr * 64 + mi * 16 + lh * 4 + r;
        float x = acc[mi][ni][r] + bc;
        if constexpr (MODE == 0) {
          ((u16*)Cout)[(size_t)row * N + col] = f2bf(x);
        } else if constexpr (MODE == 1) {
          int b = row >> 10, s = row & 1023, h = col >> 6, d = col & 63;
          ((u16*)Cout)[((size_t)(b * NHc + h) * Sc + s) * HDc + d] = f2bf(x);
        } else if constexpr (MODE == 2) {
          int b = row >> 10, s = row & 1023, h = col >> 6, d = col & 63;
          ((u16*)Cout)[((size_t)(b * NHc + h) * HDc + d) * Sc + s] = f2bf(x);
        } else {
          ((float*)Cout)[(size_t)row * N + col] = x;
        }
      }
    }
  }
}

// ---------------- energy: E = where(mask, Qs*Ks^T, Q*K^T) / 8 (f32, into d_out attn) ----------
__global__ __launch_bounds__(256) void energy_kernel(const u16* __restrict__ Qh,
                                                     const u16* __restrict__ Kh,
                                                     const u16* __restrict__ Qsh,
                                                     const u16* __restrict__ Ksh,
                                                     const int* __restrict__ mask,
                                                     float* __restrict__ E) {
  const int w = threadIdx.x >> 6, l = threadIdx.x & 63;
  const int lr = l & 15, lh = l >> 4;
  const int bh = blockIdx.z, b = bh >> 4;
  const int q0 = blockIdx.y << 4;
  const int k0 = ((blockIdx.x << 2) + w) << 4;
  const size_t hoff = (size_t)bh * Sc * HDc;
  const u16* Qp = Qh + hoff + (size_t)(q0 + lr) * HDc + lh * 8;
  const u16* Kp = Kh + hoff + (size_t)(k0 + lr) * HDc + lh * 8;
  const u16* Qsp = Qsh + hoff + (size_t)(q0 + lr) * HDc + lh * 8;
  const u16* Ksp = Ksh + hoff + (size_t)(k0 + lr) * HDc + lh * 8;
  f32x4 e = {}, es = {};
  e = mfma16(*(const bf16x8*)Qp, *(const bf16x8*)Kp, e);
  e = mfma16(*(const bf16x8*)(Qp + 32), *(const bf16x8*)(Kp + 32), e);
  es = mfma16(*(const bf16x8*)Qsp, *(const bf16x8*)Ksp, es);
  es = mfma16(*(const bf16x8*)(Qsp + 32), *(const bf16x8*)(Ksp + 32), es);
  const size_t ebase = (size_t)bh * Sc * Sc;
#pragma unroll
  for (int r = 0; r < 4; ++r) {
    int row = q0 + lh * 4 + r, col = k0 + lr;
    int mv = mask[((size_t)b * Sc + row) * Sc + col];
    E[ebase + (size_t)row * Sc + col] = (mv ? es[r] : e[r]) * 0.125f;
  }
}

// ---------------- row softmax in place (1 wave per 1024-row) ----------------
__global__ __launch_bounds__(256) void softmax_kernel(float* __restrict__ E) {
  const int w = threadIdx.x >> 6, l = threadIdx.x & 63;
  float* p = E + ((size_t)blockIdx.x * 4 + w) * Sc;
  f32x4 v[4];
#pragma unroll
  for (int j = 0; j < 4; ++j) v[j] = *(const f32x4*)(p + j * 256 + l * 4);
  float m = -1e30f;
#pragma unroll
  for (int j = 0; j < 4; ++j)
#pragma unroll
    for (int i = 0; i < 4; ++i) m = fmaxf(m, v[j][i]);
#pragma unroll
  for (int off = 32; off; off >>= 1) m = fmaxf(m, __shfl_xor(m, off));
  float s = 0.f;
#pragma unroll
  for (int j = 0; j < 4; ++j)
#pragma unroll
    for (int i = 0; i < 4; ++i) { float t = __expf(v[j][i] - m); v[j][i] = t; s += t; }
#pragma unroll
  for (int off = 32; off; off >>= 1) s += __shfl_xor(s, off);
  float inv = 1.f / s;
#pragma unroll
  for (int j = 0; j < 4; ++j) { v[j] *= inv; *(f32x4*)(p + j * 256 + l * 4) = v[j]; }
}

// ---------------- PV: ctx[b,s,h*64+d] = sum_k P[q,k] * V[k,d] ----------------
__global__ __launch_bounds__(256) void pv_kernel(const float* __restrict__ P,
                                                 const u16* __restrict__ Vt,
                                                 u16* __restrict__ ctx) {
  const int w = threadIdx.x >> 6, l = threadIdx.x & 63;
  const int lr = l & 15, lh = l >> 4;
  const int bh = blockIdx.y, b = bh >> 4, h = bh & 15;
  const int q0 = (blockIdx.x << 6) + (w << 4);
  const float* Pr = P + (size_t)bh * Sc * Sc + (size_t)(q0 + lr) * Sc + lh * 8;
  const u16* Vb = Vt + (size_t)bh * HDc * Sc + (size_t)lr * Sc + lh * 8;
  f32x4 acc[4] = {};
  for (int k0 = 0; k0 < Sc; k0 += 32) {
    f32x4 p0 = *(const f32x4*)(Pr + k0);
    f32x4 p1 = *(const f32x4*)(Pr + k0 + 4);
    union { bf16x8 v; u16 s[8]; } a;
#pragma unroll
    for (int i = 0; i < 4; ++i) { a.s[i] = f2bf(p0[i]); a.s[4 + i] = f2bf(p1[i]); }
#pragma unroll
    for (int ni = 0; ni < 4; ++ni) {
      bf16x8 bv = *(const bf16x8*)(Vb + (size_t)(ni * 16) * Sc + k0);
      acc[ni] = mfma16(a.v, bv, acc[ni]);
    }
  }
#pragma unroll
  for (int ni = 0; ni < 4; ++ni) {
    int d = ni * 16 + lr;
#pragma unroll
    for (int r = 0; r < 4; ++r) {
      int row = q0 + lh * 4 + r;
      ctx[((size_t)b * Sc + row) * Hc + h * HDc + d] = f2bf(acc[ni][r]);
    }
  }
}

extern "C" void kernel_launch(void* const* d_in, const int* in_sizes, int n_in,
                              void* d_out, int out_size, void* d_ws, size_t ws_size,
                              hipStream_t stream) {
  const float* fin[5] = { (const float*)d_in[0], (const float*)d_in[1], (const float*)d_in[2],
                          (const float*)d_in[3], (const float*)d_in[4] };
  const int* mask = (const int*)d_in[5];
  const float* W[6] = { (const float*)d_in[6], (const float*)d_in[8], (const float*)d_in[10],
                        (const float*)d_in[12], (const float*)d_in[14], (const float*)d_in[16] };
  const float* bias[6] = { (const float*)d_in[7], (const float*)d_in[9], (const float*)d_in[11],
                           (const float*)d_in[13], (const float*)d_in[15], (const float*)d_in[17] };

  float* out_x = (float*)d_out;
  float* out_attn = out_x + (size_t)Bc * Sc * Hc;

  const size_t NE = (size_t)Bc * Sc * Hc; // 4M elems
  const size_t NW = (size_t)Hc * Hc;      // 1M elems
  u16* p = (u16*)d_ws;
  u16* xin[5]; for (int i = 0; i < 5; ++i) { xin[i] = p; p += NE; }
  u16* wbf[6]; for (int i = 0; i < 6; ++i) { wbf[i] = p; p += NW; }
  u16* Qh  = p; p += NE;
  u16* Kh  = p; p += NE;
  u16* Qsh = p; p += NE;
  u16* Ksh = p; p += NE;
  u16* Vth = p; p += NE;
  u16* ctx = p; p += NE;

  for (int i = 0; i < 5; ++i)
    cvt_kernel<<<(int)(NE / 8 / 256), 256, 0, stream>>>(fin[i], xin[i], (int)(NE / 8));
  for (int i = 0; i < 6; ++i)
    cvt_kernel<<<(int)(NW / 8 / 256), 256, 0, stream>>>(W[i], wbf[i], (int)(NW / 8));

  dim3 ggrid(Hc / 128, Mrows / 128);
  gemm_bt<1><<<ggrid, 256, 0, stream>>>(xin[0], wbf[0], bias[0], Qh);
  gemm_bt<1><<<ggrid, 256, 0, stream>>>(xin[1], wbf[1], bias[1], Kh);
  gemm_bt<1><<<ggrid, 256, 0, stream>>>(xin[2], wbf[2], bias[2], Qsh);
  gemm_bt<1><<<ggrid, 256, 0, stream>>>(xin[3], wbf[3], bias[3], Ksh);
  gemm_bt<2><<<ggrid, 256, 0, stream>>>(xin[4], wbf[4], bias[4], Vth);

  energy_kernel<<<dim3(Sc / 64, Sc / 16, Bc * NHc), 256, 0, stream>>>(Qh, Kh, Qsh, Ksh, mask, out_attn);
  softmax_kernel<<<(Bc * NHc * Sc) / 4, 256, 0, stream>>>(out_attn);
  pv_kernel<<<dim3(Sc / 64, Bc * NHc), 256, 0, stream>>>(out_attn, Vth, ctx);
  gemm_bt<3><<<ggrid, 256, 0, stream>>>(ctx, wbf[5], bias[5], out_x);
}

// Round 2
// 372.347 us; speedup vs baseline: 1.7218x; 1.7218x over previous
//
#include <hip/hip_runtime.h>
#include <hip/hip_bf16.h>
#include <stdint.h>

typedef uint16_t u16;
typedef __attribute__((ext_vector_type(8))) short bf16x8;
typedef __attribute__((ext_vector_type(4))) float f32x4;

#define DEVI static __device__ __forceinline__
#define GLOAD_LDS(gptr, lptr) \
  __builtin_amdgcn_global_load_lds((const __attribute__((address_space(1))) void*)(gptr), \
                                   (__attribute__((address_space(3))) void*)(lptr), 16, 0, 0)

constexpr int Bc = 4, Sc = 1024, Hc = 1024, NHc = 16, HDc = 64;
constexpr int Mrows = Bc * Sc; // 4096

DEVI u16 f2bf(float f) {
  uint32_t u = __builtin_bit_cast(uint32_t, f);
  u += 0x7FFFu + ((u >> 16) & 1u);
  return (u16)(u >> 16);
}

DEVI f32x4 mfma16(bf16x8 a, bf16x8 b, f32x4 c) {
  return __builtin_amdgcn_mfma_f32_16x16x32_bf16(a, b, c, 0, 0, 0);
}

// ---------------- f32 -> bf16 conversion ----------------
__global__ __launch_bounds__(256) void cvt_kernel(const float* __restrict__ in,
                                                  u16* __restrict__ out, int n8) {
  int i = blockIdx.x * 256 + threadIdx.x;
  if (i >= n8) return;
  const f32x4* p = (const f32x4*)(in + (size_t)i * 8);
  f32x4 a = p[0], b = p[1];
  union { bf16x8 v; u16 s[8]; } r;
#pragma unroll
  for (int j = 0; j < 4; ++j) { r.s[j] = f2bf(a[j]); r.s[4 + j] = f2bf(b[j]); }
  *(bf16x8*)(out + (size_t)i * 8) = r.v;
}

// ---------------- mask int32 -> bitmask (each thread: 32 ints -> 1 u32) ------
__global__ __launch_bounds__(256) void maskpack_kernel(const int* __restrict__ mask,
                                                       uint32_t* __restrict__ out) {
  int i = blockIdx.x * 256 + threadIdx.x;
  const int4* p = (const int4*)(mask + (size_t)i * 32);
  uint32_t r = 0;
#pragma unroll
  for (int j = 0; j < 8; ++j) {
    int4 v = p[j];
    uint32_t nib = (v.x ? 1u : 0u) | (v.y ? 2u : 0u) | (v.z ? 4u : 0u) | (v.w ? 8u : 0u);
    r |= nib << (j * 4);
  }
  out[i] = r;
}

// ---------------- fused 5-way projection GEMM ----------------
// C[M,1024] = A[M,1024] * W[1024,1024]^T + bias, M=4096. z in [0,5):
// z<4 -> write [b,h,s,d]; z==4 -> write [b,h,d,s] (V transposed).
struct P5 { const u16* A[5]; const u16* W[5]; const float* b[5]; u16* o[5]; };

__global__ __launch_bounds__(256) void proj5_kernel(P5 args) {
  constexpr int K = 1024, BK = 32;
  __shared__ u16 As[128 * BK];
  __shared__ u16 Bs[128 * BK];
  const int z = blockIdx.z;
  const u16* __restrict__ A = args.A[z];
  const u16* __restrict__ Bw = args.W[z];
  const float* __restrict__ bias = args.b[z];
  u16* __restrict__ Cout = args.o[z];
  const int t = threadIdx.x;
  const int w = t >> 6, l = t & 63;
  const int lr = l & 15, lh = l >> 4;
  const int m0 = blockIdx.y * 128, n0 = blockIdx.x * 128;
  const int wr = w >> 1, wc = w & 1;
  f32x4 acc[4][4] = {};

  const int row_s = t >> 2, k8 = (t & 3) << 3;
  const u16* ga = A + (size_t)(m0 + row_s) * K + k8;
  const u16* gb = Bw + (size_t)(n0 + row_s) * K + k8;

  for (int kt = 0; kt < K; kt += BK) {
    GLOAD_LDS(ga + kt, As + t * 8);
    GLOAD_LDS(ga + (size_t)64 * K + kt, As + 2048 + t * 8);
    GLOAD_LDS(gb + kt, Bs + t * 8);
    GLOAD_LDS(gb + (size_t)64 * K + kt, Bs + 2048 + t * 8);
    __syncthreads();
    bf16x8 af[4], bfr[4];
#pragma unroll
    for (int mi = 0; mi < 4; ++mi)
      af[mi] = *(const bf16x8*)(As + (wr * 64 + mi * 16 + lr) * BK + lh * 8);
#pragma unroll
    for (int ni = 0; ni < 4; ++ni)
      bfr[ni] = *(const bf16x8*)(Bs + (wc * 64 + ni * 16 + lr) * BK + lh * 8);
#pragma unroll
    for (int mi = 0; mi < 4; ++mi)
#pragma unroll
      for (int ni = 0; ni < 4; ++ni)
        acc[mi][ni] = mfma16(af[mi], bfr[ni], acc[mi][ni]);
    __syncthreads();
  }

#pragma unroll
  for (int mi = 0; mi < 4; ++mi) {
#pragma unroll
    for (int ni = 0; ni < 4; ++ni) {
      int col = n0 + wc * 64 + ni * 16 + lr;
      float bc = bias[col];
      int hcol = col >> 6, dcol = col & 63;
#pragma unroll
      for (int r = 0; r < 4; ++r) {
        int rowg = m0 + wr * 64 + mi * 16 + lh * 4 + r;
        float x = acc[mi][ni][r] + bc;
        int bb = rowg >> 10, s = rowg & 1023;
        size_t idx;
        if (z == 4) idx = ((size_t)(bb * NHc + hcol) * HDc + dcol) * Sc + s;
        else        idx = ((size_t)(bb * NHc + hcol) * Sc + s) * HDc + dcol;
        Cout[idx] = f2bf(x);
      }
    }
  }
}

// ---------------- output projection GEMM (f32 out, [M,N]) ----------------
__global__ __launch_bounds__(256) void gemmo_kernel(const u16* __restrict__ A,
                                                    const u16* __restrict__ Bw,
                                                    const float* __restrict__ bias,
                                                    float* __restrict__ Cout) {
  constexpr int K = 1024, N = 1024, BK = 32;
  __shared__ u16 As[128 * BK];
  __shared__ u16 Bs[128 * BK];
  const int t = threadIdx.x;
  const int w = t >> 6, l = t & 63;
  const int lr = l & 15, lh = l >> 4;
  const int m0 = blockIdx.y * 128, n0 = blockIdx.x * 128;
  const int wr = w >> 1, wc = w & 1;
  f32x4 acc[4][4] = {};

  const int row_s = t >> 2, k8 = (t & 3) << 3;
  const u16* ga = A + (size_t)(m0 + row_s) * K + k8;
  const u16* gb = Bw + (size_t)(n0 + row_s) * K + k8;

  for (int kt = 0; kt < K; kt += BK) {
    GLOAD_LDS(ga + kt, As + t * 8);
    GLOAD_LDS(ga + (size_t)64 * K + kt, As + 2048 + t * 8);
    GLOAD_LDS(gb + kt, Bs + t * 8);
    GLOAD_LDS(gb + (size_t)64 * K + kt, Bs + 2048 + t * 8);
    __syncthreads();
    bf16x8 af[4], bfr[4];
#pragma unroll
    for (int mi = 0; mi < 4; ++mi)
      af[mi] = *(const bf16x8*)(As + (wr * 64 + mi * 16 + lr) * BK + lh * 8);
#pragma unroll
    for (int ni = 0; ni < 4; ++ni)
      bfr[ni] = *(const bf16x8*)(Bs + (wc * 64 + ni * 16 + lr) * BK + lh * 8);
#pragma unroll
    for (int mi = 0; mi < 4; ++mi)
#pragma unroll
      for (int ni = 0; ni < 4; ++ni)
        acc[mi][ni] = mfma16(af[mi], bfr[ni], acc[mi][ni]);
    __syncthreads();
  }

#pragma unroll
  for (int mi = 0; mi < 4; ++mi) {
#pragma unroll
    for (int ni = 0; ni < 4; ++ni) {
      int col = n0 + wc * 64 + ni * 16 + lr;
      float bc = bias[col];
#pragma unroll
      for (int r = 0; r < 4; ++r) {
        int rowg = m0 + wr * 64 + mi * 16 + lh * 4 + r;
        Cout[(size_t)rowg * N + col] = acc[mi][ni][r] + bc;
      }
    }
  }
}

// ---------------- fused attention: energy + select + softmax + PV ------------
// grid (64 q-tiles, 64 bh). block 256 (4 waves). LDS: E[16][1024] f32 swizzled.
// swizzle: physical f32 index(row, col) = row*1024 + (((col>>2) ^ (row&7))<<2) + (col&3)
__global__ __launch_bounds__(256) void attn_kernel(const u16* __restrict__ Qh,
                                                   const u16* __restrict__ Kh,
                                                   const u16* __restrict__ Qsh,
                                                   const u16* __restrict__ Ksh,
                                                   const u16* __restrict__ Vth,
                                                   const uint32_t* __restrict__ mbits,
                                                   float* __restrict__ Pout,
                                                   u16* __restrict__ ctx) {
  __shared__ float E[16 * 1024]; // 64 KB
  const int t = threadIdx.x, w = t >> 6, l = t & 63;
  const int lr = l & 15, lh = l >> 4;
  const int q0 = blockIdx.x << 4;
  const int bh = blockIdx.y, b = bh >> 4, h = bh & 15;
  const size_t hoff = (size_t)bh * Sc * HDc;

  // ---- mask words: rows lh*4+r, cols [w*256, w*256+256) -> 8 u32 each ----
  uint32_t mw[4][8];
  {
    const uint32_t* mrow = mbits + ((size_t)b * Sc + q0) * 32 + w * 8;
#pragma unroll
    for (int r = 0; r < 4; ++r) {
      const uint32_t* pr = mrow + (size_t)(lh * 4 + r) * 32;
      *(uint4*)&mw[r][0] = *(const uint4*)pr;
      *(uint4*)&mw[r][4] = *(const uint4*)(pr + 4);
    }
  }

  // ---- energy: wave w covers k in [w*256, w*256+256) ----
  const u16* Qp = Qh + hoff + (size_t)(q0 + lr) * HDc + lh * 8;
  const u16* Qsp = Qsh + hoff + (size_t)(q0 + lr) * HDc + lh * 8;
  bf16x8 qf0 = *(const bf16x8*)Qp, qf1 = *(const bf16x8*)(Qp + 32);
  bf16x8 sf0 = *(const bf16x8*)Qsp, sf1 = *(const bf16x8*)(Qsp + 32);

  for (int kt = 0; kt < 16; ++kt) {
    int k0 = (w << 8) + (kt << 4);
    const u16* Kp = Kh + hoff + (size_t)(k0 + lr) * HDc + lh * 8;
    const u16* Ksp = Ksh + hoff + (size_t)(k0 + lr) * HDc + lh * 8;
    f32x4 e = {}, es = {};
    e = mfma16(qf0, *(const bf16x8*)Kp, e);
    e = mfma16(qf1, *(const bf16x8*)(Kp + 32), e);
    es = mfma16(sf0, *(const bf16x8*)Ksp, es);
    es = mfma16(sf1, *(const bf16x8*)(Ksp + 32), es);
    int col = k0 + lr;
    int g = col >> 2, c3 = col & 3;
#pragma unroll
    for (int r = 0; r < 4; ++r) {
      int row = lh * 4 + r;
      uint32_t mv = (mw[r][kt >> 1] >> (((kt & 1) << 4) + lr)) & 1u;
      E[row * 1024 + (((g ^ (row & 7)) << 2) | c3)] = (mv ? es[r] : e[r]) * 0.125f;
    }
  }
  __syncthreads();

  // ---- softmax: wave w handles rows w*4 .. w*4+3 ----
  float* Pbase = Pout + ((size_t)bh * Sc + q0) * Sc;
#pragma unroll
  for (int rr = 0; rr < 4; ++rr) {
    int row = (w << 2) + rr;
    int sw = row & 7;
    f32x4 v[4];
#pragma unroll
    for (int j = 0; j < 4; ++j)
      v[j] = *(const f32x4*)(E + row * 1024 + (((j * 64 + l) ^ sw) << 2));
    float m = -1e30f;
#pragma unroll
    for (int j = 0; j < 4; ++j)
      m = fmaxf(m, fmaxf(fmaxf(v[j][0], v[j][1]), fmaxf(v[j][2], v[j][3])));
#pragma unroll
    for (int off = 32; off; off >>= 1) m = fmaxf(m, __shfl_xor(m, off));
    float s = 0.f;
#pragma unroll
    for (int j = 0; j < 4; ++j)
#pragma unroll
      for (int i = 0; i < 4; ++i) { float tt = __expf(v[j][i] - m); v[j][i] = tt; s += tt; }
#pragma unroll
    for (int off = 32; off; off >>= 1) s += __shfl_xor(s, off);
    float inv = 1.f / s;
#pragma unroll
    for (int j = 0; j < 4; ++j) {
      v[j] *= inv;
      *(f32x4*)(E + row * 1024 + (((j * 64 + l) ^ sw) << 2)) = v[j];
      *(f32x4*)(Pbase + (size_t)row * Sc + j * 256 + l * 4) = v[j];
    }
  }
  __syncthreads();

  // ---- PV: wave w handles d-cols [w*16, w*16+16) ----
  const u16* Vb = Vth + ((size_t)bh * HDc + (w << 4) + lr) * Sc + lh * 8;
  f32x4 acc = {};
  const int swp = lr & 7;
  for (int k0 = 0; k0 < Sc; k0 += 32) {
    int g0 = (k0 >> 2) + lh * 2;
    f32x4 p0 = *(const f32x4*)(E + lr * 1024 + ((g0 ^ swp) << 2));
    f32x4 p1 = *(const f32x4*)(E + lr * 1024 + (((g0 + 1) ^ swp) << 2));
    union { bf16x8 v; u16 s[8]; } a;
#pragma unroll
    for (int i = 0; i < 4; ++i) { a.s[i] = f2bf(p0[i]); a.s[4 + i] = f2bf(p1[i]); }
    bf16x8 bv = *(const bf16x8*)(Vb + k0);
    acc = mfma16(a.v, bv, acc);
  }
#pragma unroll
  for (int r = 0; r < 4; ++r) {
    int row = q0 + (lh << 2) + r;
    ctx[((size_t)b * Sc + row) * Hc + (h << 6) + (w << 4) + lr] = f2bf(acc[r]);
  }
}

extern "C" void kernel_launch(void* const* d_in, const int* in_sizes, int n_in,
                              void* d_out, int out_size, void* d_ws, size_t ws_size,
                              hipStream_t stream) {
  const float* fin[5] = { (const float*)d_in[0], (const float*)d_in[1], (const float*)d_in[2],
                          (const float*)d_in[3], (const float*)d_in[4] };
  const int* mask = (const int*)d_in[5];
  const float* W[6] = { (const float*)d_in[6], (const float*)d_in[8], (const float*)d_in[10],
                        (const float*)d_in[12], (const float*)d_in[14], (const float*)d_in[16] };
  const float* bias[6] = { (const float*)d_in[7], (const float*)d_in[9], (const float*)d_in[11],
                           (const float*)d_in[13], (const float*)d_in[15], (const float*)d_in[17] };

  float* out_x = (float*)d_out;
  float* out_attn = out_x + (size_t)Bc * Sc * Hc;

  const size_t NE = (size_t)Bc * Sc * Hc; // 4M elems
  const size_t NW = (size_t)Hc * Hc;      // 1M elems
  u16* p = (u16*)d_ws;
  u16* xin[5]; for (int i = 0; i < 5; ++i) { xin[i] = p; p += NE; }
  u16* wbf[6]; for (int i = 0; i < 6; ++i) { wbf[i] = p; p += NW; }
  u16* Qh  = p; p += NE;
  u16* Kh  = p; p += NE;
  u16* Qsh = p; p += NE;
  u16* Ksh = p; p += NE;
  u16* Vth = p; p += NE;
  u16* ctx = p; p += NE;
  // mask bitmask reuses xin[0]'s space AFTER proj5 is done with it (512 KB << 8 MB)
  uint32_t* mbits = (uint32_t*)xin[0];

  for (int i = 0; i < 5; ++i)
    cvt_kernel<<<(int)(NE / 8 / 256), 256, 0, stream>>>(fin[i], xin[i], (int)(NE / 8));
  for (int i = 0; i < 6; ++i)
    cvt_kernel<<<(int)(NW / 8 / 256), 256, 0, stream>>>(W[i], wbf[i], (int)(NW / 8));

  P5 args;
  u16* projout[5] = { Qh, Kh, Qsh, Ksh, Vth };
  for (int i = 0; i < 5; ++i) { args.A[i] = xin[i]; args.W[i] = wbf[i]; args.b[i] = bias[i]; args.o[i] = projout[i]; }
  proj5_kernel<<<dim3(Hc / 128, Mrows / 128, 5), 256, 0, stream>>>(args);

  // pack mask bits (after proj5 no longer needs xin[0])
  maskpack_kernel<<<(int)((size_t)Bc * Sc * Sc / 32 / 256), 256, 0, stream>>>(mask, mbits);

  attn_kernel<<<dim3(Sc / 16, Bc * NHc), 256, 0, stream>>>(Qh, Kh, Qsh, Ksh, Vth, mbits, out_attn, ctx);

  gemmo_kernel<<<dim3(Hc / 128, Mrows / 128), 256, 0, stream>>>(ctx, wbf[5], bias[5], out_x);
}

// Round 3
// 369.620 us; speedup vs baseline: 1.7345x; 1.0074x over previous
//
#include <hip/hip_runtime.h>
#include <hip/hip_bf16.h>
#include <stdint.h>

typedef uint16_t u16;
typedef __attribute__((ext_vector_type(8))) short bf16x8;
typedef __attribute__((ext_vector_type(4))) float f32x4;

#define DEVI static __device__ __forceinline__
#define GLOAD_LDS(gptr, lptr) \
  __builtin_amdgcn_global_load_lds((const __attribute__((address_space(1))) void*)(gptr), \
                                   (__attribute__((address_space(3))) void*)(lptr), 16, 0, 0)

constexpr int Bc = 4, Sc = 1024, Hc = 1024, NHc = 16, HDc = 64;
constexpr int Mrows = Bc * Sc; // 4096

DEVI u16 f2bf(float f) {
  uint32_t u = __builtin_bit_cast(uint32_t, f);
  u += 0x7FFFu + ((u >> 16) & 1u);
  return (u16)(u >> 16);
}
DEVI float bf2f(u16 x) { return __builtin_bit_cast(float, (uint32_t)x << 16); }

DEVI f32x4 mfma16(bf16x8 a, bf16x8 b, f32x4 c) {
  return __builtin_amdgcn_mfma_f32_16x16x32_bf16(a, b, c, 0, 0, 0);
}

// ---------------- f32 -> bf16 conversion ----------------
__global__ __launch_bounds__(256) void cvt_kernel(const float* __restrict__ in,
                                                  u16* __restrict__ out, int n8) {
  int i = blockIdx.x * 256 + threadIdx.x;
  if (i >= n8) return;
  const f32x4* p = (const f32x4*)(in + (size_t)i * 8);
  f32x4 a = p[0], b = p[1];
  union { bf16x8 v; u16 s[8]; } r;
#pragma unroll
  for (int j = 0; j < 4; ++j) { r.s[j] = f2bf(a[j]); r.s[4 + j] = f2bf(b[j]); }
  *(bf16x8*)(out + (size_t)i * 8) = r.v;
}

// ---------------- mask int32 -> bitmask ----------------
__global__ __launch_bounds__(256) void maskpack_kernel(const int* __restrict__ mask,
                                                       uint32_t* __restrict__ out) {
  int i = blockIdx.x * 256 + threadIdx.x;
  const int4* p = (const int4*)(mask + (size_t)i * 32);
  uint32_t r = 0;
#pragma unroll
  for (int j = 0; j < 8; ++j) {
    int4 v = p[j];
    uint32_t nib = (v.x ? 1u : 0u) | (v.y ? 2u : 0u) | (v.z ? 4u : 0u) | (v.w ? 8u : 0u);
    r |= nib << (j * 4);
  }
  out[i] = r;
}

// ---------------- fused 5-way projection GEMM ----------------
struct P5 { const u16* A[5]; const u16* W[5]; const float* b[5]; u16* o[5]; };

__global__ __launch_bounds__(256) void proj5_kernel(P5 args) {
  constexpr int K = 1024, BK = 32;
  __shared__ u16 As[128 * BK];
  __shared__ u16 Bs[128 * BK];
  const int z = blockIdx.z;
  const u16* __restrict__ A = args.A[z];
  const u16* __restrict__ Bw = args.W[z];
  const float* __restrict__ bias = args.b[z];
  u16* __restrict__ Cout = args.o[z];
  const int t = threadIdx.x;
  const int w = t >> 6, l = t & 63;
  const int lr = l & 15, lh = l >> 4;
  const int m0 = blockIdx.y * 128, n0 = blockIdx.x * 128;
  const int wr = w >> 1, wc = w & 1;
  f32x4 acc[4][4] = {};

  const int row_s = t >> 2, k8 = (t & 3) << 3;
  const u16* ga = A + (size_t)(m0 + row_s) * K + k8;
  const u16* gb = Bw + (size_t)(n0 + row_s) * K + k8;

  for (int kt = 0; kt < K; kt += BK) {
    GLOAD_LDS(ga + kt, As + t * 8);
    GLOAD_LDS(ga + (size_t)64 * K + kt, As + 2048 + t * 8);
    GLOAD_LDS(gb + kt, Bs + t * 8);
    GLOAD_LDS(gb + (size_t)64 * K + kt, Bs + 2048 + t * 8);
    __syncthreads();
    bf16x8 af[4], bfr[4];
#pragma unroll
    for (int mi = 0; mi < 4; ++mi)
      af[mi] = *(const bf16x8*)(As + (wr * 64 + mi * 16 + lr) * BK + lh * 8);
#pragma unroll
    for (int ni = 0; ni < 4; ++ni)
      bfr[ni] = *(const bf16x8*)(Bs + (wc * 64 + ni * 16 + lr) * BK + lh * 8);
#pragma unroll
    for (int mi = 0; mi < 4; ++mi)
#pragma unroll
      for (int ni = 0; ni < 4; ++ni)
        acc[mi][ni] = mfma16(af[mi], bfr[ni], acc[mi][ni]);
    __syncthreads();
  }

#pragma unroll
  for (int mi = 0; mi < 4; ++mi) {
#pragma unroll
    for (int ni = 0; ni < 4; ++ni) {
      int col = n0 + wc * 64 + ni * 16 + lr;
      float bc = bias[col];
      int hcol = col >> 6, dcol = col & 63;
      int rbase = m0 + wr * 64 + mi * 16 + lh * 4;
      int bb = rbase >> 10, sb = rbase & 1023;
      if (z == 4) {
        // V transposed [b,h,d,s]: 4 consecutive s -> one 8B store
        ushort4 pk;
        pk.x = f2bf(acc[mi][ni][0] + bc);
        pk.y = f2bf(acc[mi][ni][1] + bc);
        pk.z = f2bf(acc[mi][ni][2] + bc);
        pk.w = f2bf(acc[mi][ni][3] + bc);
        *(ushort4*)&Cout[((size_t)(bb * NHc + hcol) * HDc + dcol) * Sc + sb] = pk;
      } else {
#pragma unroll
        for (int r = 0; r < 4; ++r)
          Cout[((size_t)(bb * NHc + hcol) * Sc + (sb + r)) * HDc + dcol] =
              f2bf(acc[mi][ni][r] + bc);
      }
    }
  }
}

// ---------------- output projection GEMM (f32 out, [M,N]) ----------------
__global__ __launch_bounds__(256) void gemmo_kernel(const u16* __restrict__ A,
                                                    const u16* __restrict__ Bw,
                                                    const float* __restrict__ bias,
                                                    float* __restrict__ Cout) {
  constexpr int K = 1024, N = 1024, BK = 32;
  __shared__ u16 As[128 * BK];
  __shared__ u16 Bs[128 * BK];
  const int t = threadIdx.x;
  const int w = t >> 6, l = t & 63;
  const int lr = l & 15, lh = l >> 4;
  const int m0 = blockIdx.y * 128, n0 = blockIdx.x * 128;
  const int wr = w >> 1, wc = w & 1;
  f32x4 acc[4][4] = {};

  const int row_s = t >> 2, k8 = (t & 3) << 3;
  const u16* ga = A + (size_t)(m0 + row_s) * K + k8;
  const u16* gb = Bw + (size_t)(n0 + row_s) * K + k8;

  for (int kt = 0; kt < K; kt += BK) {
    GLOAD_LDS(ga + kt, As + t * 8);
    GLOAD_LDS(ga + (size_t)64 * K + kt, As + 2048 + t * 8);
    GLOAD_LDS(gb + kt, Bs + t * 8);
    GLOAD_LDS(gb + (size_t)64 * K + kt, Bs + 2048 + t * 8);
    __syncthreads();
    bf16x8 af[4], bfr[4];
#pragma unroll
    for (int mi = 0; mi < 4; ++mi)
      af[mi] = *(const bf16x8*)(As + (wr * 64 + mi * 16 + lr) * BK + lh * 8);
#pragma unroll
    for (int ni = 0; ni < 4; ++ni)
      bfr[ni] = *(const bf16x8*)(Bs + (wc * 64 + ni * 16 + lr) * BK + lh * 8);
#pragma unroll
    for (int mi = 0; mi < 4; ++mi)
#pragma unroll
      for (int ni = 0; ni < 4; ++ni)
        acc[mi][ni] = mfma16(af[mi], bfr[ni], acc[mi][ni]);
    __syncthreads();
  }

#pragma unroll
  for (int mi = 0; mi < 4; ++mi) {
#pragma unroll
    for (int ni = 0; ni < 4; ++ni) {
      int col = n0 + wc * 64 + ni * 16 + lr;
      float bc = bias[col];
#pragma unroll
      for (int r = 0; r < 4; ++r) {
        int rowg = m0 + wr * 64 + mi * 16 + lh * 4 + r;
        Cout[(size_t)rowg * N + col] = acc[mi][ni][r] + bc;
      }
    }
  }
}

// ---------------- fused attention: energy + select + softmax + PV ------------
// E in LDS as bf16 [16][1024], swizzled at 16B granularity:
//   u16 index(row,k) = row*1024 + (((k>>3) ^ (row&7)) << 3) | (k&7)
__global__ __launch_bounds__(256, 5) void attn_kernel(const u16* __restrict__ Qh,
                                                      const u16* __restrict__ Kh,
                                                      const u16* __restrict__ Qsh,
                                                      const u16* __restrict__ Ksh,
                                                      const u16* __restrict__ Vth,
                                                      const uint32_t* __restrict__ mbits,
                                                      float* __restrict__ Pout,
                                                      u16* __restrict__ ctx) {
  __shared__ __align__(16) u16 E[16 * 1024]; // 32 KB
  const int t = threadIdx.x, w = t >> 6, l = t & 63;
  const int lr = l & 15, lh = l >> 4;
  // XCD-aware remap: 64 q-tiles of one head stay on one XCD
  int lid = blockIdx.y * 64 + blockIdx.x;
  int xcd = lid & 7, j = lid >> 3;
  int bh = xcd * 8 + (j >> 6);
  int q0 = (j & 63) << 4;
  const int b = bh >> 4, h = bh & 15;
  const size_t hoff = (size_t)bh * Sc * HDc;

  // ---- mask words: rows lh*4+r, cols [w*256, w*256+256) ----
  uint32_t mw[4][8];
  {
    const uint32_t* mrow = mbits + ((size_t)b * Sc + q0) * 32 + w * 8;
#pragma unroll
    for (int r = 0; r < 4; ++r) {
      const uint32_t* pr = mrow + (size_t)(lh * 4 + r) * 32;
      *(uint4*)&mw[r][0] = *(const uint4*)pr;
      *(uint4*)&mw[r][4] = *(const uint4*)(pr + 4);
    }
  }

  // ---- energy: wave w covers k in [w*256, w*256+256) ----
  const u16* Qp = Qh + hoff + (size_t)(q0 + lr) * HDc + lh * 8;
  const u16* Qsp = Qsh + hoff + (size_t)(q0 + lr) * HDc + lh * 8;
  bf16x8 qf0 = *(const bf16x8*)Qp, qf1 = *(const bf16x8*)(Qp + 32);
  bf16x8 sf0 = *(const bf16x8*)Qsp, sf1 = *(const bf16x8*)(Qsp + 32);

  for (int kt = 0; kt < 16; ++kt) {
    int k0 = (w << 8) + (kt << 4);
    const u16* Kp = Kh + hoff + (size_t)(k0 + lr) * HDc + lh * 8;
    const u16* Ksp = Ksh + hoff + (size_t)(k0 + lr) * HDc + lh * 8;
    f32x4 e = {}, es = {};
    e = mfma16(qf0, *(const bf16x8*)Kp, e);
    e = mfma16(qf1, *(const bf16x8*)(Kp + 32), e);
    es = mfma16(sf0, *(const bf16x8*)Ksp, es);
    es = mfma16(sf1, *(const bf16x8*)(Ksp + 32), es);
    int col = k0 + lr;
#pragma unroll
    for (int r = 0; r < 4; ++r) {
      int row = lh * 4 + r;
      uint32_t mv = (mw[r][kt >> 1] >> (((kt & 1) << 4) + lr)) & 1u;
      E[(row << 10) + ((((col >> 3) ^ (row & 7)) << 3) | (col & 7))] =
          f2bf((mv ? es[r] : e[r]) * 0.125f);
    }
  }
  __syncthreads();

  // ---- softmax: wave w handles rows w*4 .. w*4+3; lane owns k=j*256+l*4 ----
  float* Pbase = Pout + ((size_t)bh * Sc + q0) * Sc;
#pragma unroll
  for (int rr = 0; rr < 4; ++rr) {
    int row = (w << 2) + rr;
    int sw = row & 7;
    float v[4][4];
#pragma unroll
    for (int jj = 0; jj < 4; ++jj) {
      int k = jj * 256 + (l << 2);
      ushort4 raw = *(const ushort4*)&E[(row << 10) + ((((k >> 3) ^ sw) << 3) | (k & 7))];
      v[jj][0] = bf2f(raw.x); v[jj][1] = bf2f(raw.y);
      v[jj][2] = bf2f(raw.z); v[jj][3] = bf2f(raw.w);
    }
    float m = -1e30f;
#pragma unroll
    for (int jj = 0; jj < 4; ++jj)
      m = fmaxf(m, fmaxf(fmaxf(v[jj][0], v[jj][1]), fmaxf(v[jj][2], v[jj][3])));
#pragma unroll
    for (int off = 32; off; off >>= 1) m = fmaxf(m, __shfl_xor(m, off));
    float s = 0.f;
#pragma unroll
    for (int jj = 0; jj < 4; ++jj)
#pragma unroll
      for (int i = 0; i < 4; ++i) { float tt = __expf(v[jj][i] - m); v[jj][i] = tt; s += tt; }
#pragma unroll
    for (int off = 32; off; off >>= 1) s += __shfl_xor(s, off);
    float inv = 1.f / s;
#pragma unroll
    for (int jj = 0; jj < 4; ++jj) {
      int k = jj * 256 + (l << 2);
      f32x4 pv = { v[jj][0] * inv, v[jj][1] * inv, v[jj][2] * inv, v[jj][3] * inv };
      *(f32x4*)(Pbase + (size_t)row * Sc + k) = pv;
      ushort4 wb;
      wb.x = f2bf(pv[0]); wb.y = f2bf(pv[1]); wb.z = f2bf(pv[2]); wb.w = f2bf(pv[3]);
      *(ushort4*)&E[(row << 10) + ((((k >> 3) ^ sw) << 3) | (k & 7))] = wb;
    }
  }
  __syncthreads();

  // ---- PV: wave w handles d-cols [w*16, w*16+16); A-frags straight from LDS ----
  const u16* Vb = Vth + ((size_t)bh * HDc + (w << 4) + lr) * Sc + lh * 8;
  const int swp = lr & 7;
  f32x4 acc0 = {}, acc1 = {};
  for (int k0 = 0; k0 < 1024; k0 += 64) {
    int ka = k0 + (lh << 3);
    bf16x8 a0 = *(const bf16x8*)&E[(lr << 10) + (((ka >> 3) ^ swp) << 3)];
    bf16x8 b0 = *(const bf16x8*)(Vb + k0);
    acc0 = mfma16(a0, b0, acc0);
    int kb = ka + 32;
    bf16x8 a1 = *(const bf16x8*)&E[(lr << 10) + (((kb >> 3) ^ swp) << 3)];
    bf16x8 b1 = *(const bf16x8*)(Vb + k0 + 32);
    acc1 = mfma16(a1, b1, acc1);
  }
  f32x4 acc = acc0 + acc1;
#pragma unroll
  for (int r = 0; r < 4; ++r) {
    int row = q0 + (lh << 2) + r;
    ctx[((size_t)b * Sc + row) * Hc + (h << 6) + (w << 4) + lr] = f2bf(acc[r]);
  }
}

extern "C" void kernel_launch(void* const* d_in, const int* in_sizes, int n_in,
                              void* d_out, int out_size, void* d_ws, size_t ws_size,
                              hipStream_t stream) {
  const float* fin[5] = { (const float*)d_in[0], (const float*)d_in[1], (const float*)d_in[2],
                          (const float*)d_in[3], (const float*)d_in[4] };
  const int* mask = (const int*)d_in[5];
  const float* W[6] = { (const float*)d_in[6], (const float*)d_in[8], (const float*)d_in[10],
                        (const float*)d_in[12], (const float*)d_in[14], (const float*)d_in[16] };
  const float* bias[6] = { (const float*)d_in[7], (const float*)d_in[9], (const float*)d_in[11],
                           (const float*)d_in[13], (const float*)d_in[15], (const float*)d_in[17] };

  float* out_x = (float*)d_out;
  float* out_attn = out_x + (size_t)Bc * Sc * Hc;

  const size_t NE = (size_t)Bc * Sc * Hc; // 4M elems
  const size_t NW = (size_t)Hc * Hc;      // 1M elems
  u16* p = (u16*)d_ws;
  u16* xin[5]; for (int i = 0; i < 5; ++i) { xin[i] = p; p += NE; }
  u16* wbf[6]; for (int i = 0; i < 6; ++i) { wbf[i] = p; p += NW; }
  u16* Qh  = p; p += NE;
  u16* Kh  = p; p += NE;
  u16* Qsh = p; p += NE;
  u16* Ksh = p; p += NE;
  u16* Vth = p; p += NE;
  u16* ctx = p; p += NE;
  uint32_t* mbits = (uint32_t*)xin[0]; // reused after proj5

  for (int i = 0; i < 5; ++i)
    cvt_kernel<<<(int)(NE / 8 / 256), 256, 0, stream>>>(fin[i], xin[i], (int)(NE / 8));
  for (int i = 0; i < 6; ++i)
    cvt_kernel<<<(int)(NW / 8 / 256), 256, 0, stream>>>(W[i], wbf[i], (int)(NW / 8));

  P5 args;
  u16* projout[5] = { Qh, Kh, Qsh, Ksh, Vth };
  for (int i = 0; i < 5; ++i) { args.A[i] = xin[i]; args.W[i] = wbf[i]; args.b[i] = bias[i]; args.o[i] = projout[i]; }
  proj5_kernel<<<dim3(Hc / 128, Mrows / 128, 5), 256, 0, stream>>>(args);

  maskpack_kernel<<<(int)((size_t)Bc * Sc * Sc / 32 / 256), 256, 0, stream>>>(mask, mbits);

  attn_kernel<<<dim3(Sc / 16, Bc * NHc), 256, 0, stream>>>(Qh, Kh, Qsh, Ksh, Vth, mbits, out_attn, ctx);

  gemmo_kernel<<<dim3(Hc / 128, Mrows / 128), 256, 0, stream>>>(ctx, wbf[5], bias[5], out_x);
}

// Round 4
// 369.395 us; speedup vs baseline: 1.7356x; 1.0006x over previous
//
#include <hip/hip_runtime.h>
#include <hip/hip_bf16.h>
#include <stdint.h>

typedef uint16_t u16;
typedef __attribute__((ext_vector_type(8))) short bf16x8;
typedef __attribute__((ext_vector_type(4))) float f32x4;

#define DEVI static __device__ __forceinline__
#define GLOAD_LDS(gptr, lptr) \
  __builtin_amdgcn_global_load_lds((const __attribute__((address_space(1))) void*)(gptr), \
                                   (__attribute__((address_space(3))) void*)(lptr), 16, 0, 0)

constexpr int Bc = 4, Sc = 1024, Hc = 1024, NHc = 16, HDc = 64;
constexpr int Mrows = Bc * Sc; // 4096

DEVI u16 f2bf(float f) {
  uint32_t u = __builtin_bit_cast(uint32_t, f);
  u += 0x7FFFu + ((u >> 16) & 1u);
  return (u16)(u >> 16);
}
DEVI float bf2f(u16 x) { return __builtin_bit_cast(float, (uint32_t)x << 16); }

DEVI f32x4 mfma16(bf16x8 a, bf16x8 b, f32x4 c) {
  return __builtin_amdgcn_mfma_f32_16x16x32_bf16(a, b, c, 0, 0, 0);
}

// ---------------- f32 -> bf16 conversion ----------------
__global__ __launch_bounds__(256) void cvt_kernel(const float* __restrict__ in,
                                                  u16* __restrict__ out, int n8) {
  int i = blockIdx.x * 256 + threadIdx.x;
  if (i >= n8) return;
  const f32x4* p = (const f32x4*)(in + (size_t)i * 8);
  f32x4 a = p[0], b = p[1];
  union { bf16x8 v; u16 s[8]; } r;
#pragma unroll
  for (int j = 0; j < 4; ++j) { r.s[j] = f2bf(a[j]); r.s[4 + j] = f2bf(b[j]); }
  *(bf16x8*)(out + (size_t)i * 8) = r.v;
}

// ---------------- mask int32 -> bitmask ----------------
__global__ __launch_bounds__(256) void maskpack_kernel(const int* __restrict__ mask,
                                                       uint32_t* __restrict__ out) {
  int i = blockIdx.x * 256 + threadIdx.x;
  const int4* p = (const int4*)(mask + (size_t)i * 32);
  uint32_t r = 0;
#pragma unroll
  for (int j = 0; j < 8; ++j) {
    int4 v = p[j];
    uint32_t nib = (v.x ? 1u : 0u) | (v.y ? 2u : 0u) | (v.z ? 4u : 0u) | (v.w ? 8u : 0u);
    r |= nib << (j * 4);
  }
  out[i] = r;
}

// ---------------- fused 5-way projection GEMM ----------------
struct P5 { const u16* A[5]; const u16* W[5]; const float* b[5]; u16* o[5]; };

__global__ __launch_bounds__(256) void proj5_kernel(P5 args) {
  constexpr int K = 1024, BK = 32;
  __shared__ u16 As[128 * BK];
  __shared__ u16 Bs[128 * BK];
  const int z = blockIdx.z;
  const u16* __restrict__ A = args.A[z];
  const u16* __restrict__ Bw = args.W[z];
  const float* __restrict__ bias = args.b[z];
  u16* __restrict__ Cout = args.o[z];
  const int t = threadIdx.x;
  const int w = t >> 6, l = t & 63;
  const int lr = l & 15, lh = l >> 4;
  const int m0 = blockIdx.y * 128, n0 = blockIdx.x * 128;
  const int wr = w >> 1, wc = w & 1;
  f32x4 acc[4][4] = {};

  const int row_s = t >> 2, k8 = (t & 3) << 3;
  const u16* ga = A + (size_t)(m0 + row_s) * K + k8;
  const u16* gb = Bw + (size_t)(n0 + row_s) * K + k8;

  for (int kt = 0; kt < K; kt += BK) {
    GLOAD_LDS(ga + kt, As + t * 8);
    GLOAD_LDS(ga + (size_t)64 * K + kt, As + 2048 + t * 8);
    GLOAD_LDS(gb + kt, Bs + t * 8);
    GLOAD_LDS(gb + (size_t)64 * K + kt, Bs + 2048 + t * 8);
    __syncthreads();
    bf16x8 af[4], bfr[4];
#pragma unroll
    for (int mi = 0; mi < 4; ++mi)
      af[mi] = *(const bf16x8*)(As + (wr * 64 + mi * 16 + lr) * BK + lh * 8);
#pragma unroll
    for (int ni = 0; ni < 4; ++ni)
      bfr[ni] = *(const bf16x8*)(Bs + (wc * 64 + ni * 16 + lr) * BK + lh * 8);
#pragma unroll
    for (int mi = 0; mi < 4; ++mi)
#pragma unroll
      for (int ni = 0; ni < 4; ++ni)
        acc[mi][ni] = mfma16(af[mi], bfr[ni], acc[mi][ni]);
    __syncthreads();
  }

#pragma unroll
  for (int mi = 0; mi < 4; ++mi) {
#pragma unroll
    for (int ni = 0; ni < 4; ++ni) {
      int col = n0 + wc * 64 + ni * 16 + lr;
      float bc = bias[col];
      int hcol = col >> 6, dcol = col & 63;
      int rbase = m0 + wr * 64 + mi * 16 + lh * 4;
      int bb = rbase >> 10, sb = rbase & 1023;
      if (z == 4) {
        ushort4 pk;
        pk.x = f2bf(acc[mi][ni][0] + bc);
        pk.y = f2bf(acc[mi][ni][1] + bc);
        pk.z = f2bf(acc[mi][ni][2] + bc);
        pk.w = f2bf(acc[mi][ni][3] + bc);
        *(ushort4*)&Cout[((size_t)(bb * NHc + hcol) * HDc + dcol) * Sc + sb] = pk;
      } else {
#pragma unroll
        for (int r = 0; r < 4; ++r)
          Cout[((size_t)(bb * NHc + hcol) * Sc + (sb + r)) * HDc + dcol] =
              f2bf(acc[mi][ni][r] + bc);
      }
    }
  }
}

// ---------------- output projection GEMM (f32 out, [M,N]) ----------------
__global__ __launch_bounds__(256) void gemmo_kernel(const u16* __restrict__ A,
                                                    const u16* __restrict__ Bw,
                                                    const float* __restrict__ bias,
                                                    float* __restrict__ Cout) {
  constexpr int K = 1024, N = 1024, BK = 32;
  __shared__ u16 As[128 * BK];
  __shared__ u16 Bs[128 * BK];
  const int t = threadIdx.x;
  const int w = t >> 6, l = t & 63;
  const int lr = l & 15, lh = l >> 4;
  const int m0 = blockIdx.y * 128, n0 = blockIdx.x * 128;
  const int wr = w >> 1, wc = w & 1;
  f32x4 acc[4][4] = {};

  const int row_s = t >> 2, k8 = (t & 3) << 3;
  const u16* ga = A + (size_t)(m0 + row_s) * K + k8;
  const u16* gb = Bw + (size_t)(n0 + row_s) * K + k8;

  for (int kt = 0; kt < K; kt += BK) {
    GLOAD_LDS(ga + kt, As + t * 8);
    GLOAD_LDS(ga + (size_t)64 * K + kt, As + 2048 + t * 8);
    GLOAD_LDS(gb + kt, Bs + t * 8);
    GLOAD_LDS(gb + (size_t)64 * K + kt, Bs + 2048 + t * 8);
    __syncthreads();
    bf16x8 af[4], bfr[4];
#pragma unroll
    for (int mi = 0; mi < 4; ++mi)
      af[mi] = *(const bf16x8*)(As + (wr * 64 + mi * 16 + lr) * BK + lh * 8);
#pragma unroll
    for (int ni = 0; ni < 4; ++ni)
      bfr[ni] = *(const bf16x8*)(Bs + (wc * 64 + ni * 16 + lr) * BK + lh * 8);
#pragma unroll
    for (int mi = 0; mi < 4; ++mi)
#pragma unroll
      for (int ni = 0; ni < 4; ++ni)
        acc[mi][ni] = mfma16(af[mi], bfr[ni], acc[mi][ni]);
    __syncthreads();
  }

#pragma unroll
  for (int mi = 0; mi < 4; ++mi) {
#pragma unroll
    for (int ni = 0; ni < 4; ++ni) {
      int col = n0 + wc * 64 + ni * 16 + lr;
      float bc = bias[col];
#pragma unroll
      for (int r = 0; r < 4; ++r) {
        int rowg = m0 + wr * 64 + mi * 16 + lh * 4 + r;
        Cout[(size_t)rowg * N + col] = acc[mi][ni][r] + bc;
      }
    }
  }
}

// ---------------- fused attention: energy + select + softmax + PV ------------
// E in LDS as bf16 [16][1024], swizzled at 16B granularity:
//   u16 index(row,k) = row*1024 + (((k>>3) ^ (row&7)) << 3) | (k&7)
__global__ __launch_bounds__(256, 4) void attn_kernel(const u16* __restrict__ Qh,
                                                      const u16* __restrict__ Kh,
                                                      const u16* __restrict__ Qsh,
                                                      const u16* __restrict__ Ksh,
                                                      const u16* __restrict__ Vth,
                                                      const uint32_t* __restrict__ mbits,
                                                      float* __restrict__ Pout,
                                                      u16* __restrict__ ctx) {
  __shared__ __align__(16) u16 E[16 * 1024]; // 32 KB
  const int t = threadIdx.x, w = t >> 6, l = t & 63;
  const int lr = l & 15, lh = l >> 4;
  // XCD-aware remap: 64 q-tiles of one head stay on one XCD
  int lid = blockIdx.y * 64 + blockIdx.x;
  int xcd = lid & 7, j = lid >> 3;
  int bh = xcd * 8 + (j >> 6);
  int q0 = (j & 63) << 4;
  const int b = bh >> 4, h = bh & 15;
  const size_t hoff = (size_t)bh * Sc * HDc;

  // ---- mask words: rows lh*4+r, cols [w*256, w*256+256) ----
  uint32_t mw[4][8];
  {
    const uint32_t* mrow = mbits + ((size_t)b * Sc + q0) * 32 + w * 8;
#pragma unroll
    for (int r = 0; r < 4; ++r) {
      const uint32_t* pr = mrow + (size_t)(lh * 4 + r) * 32;
      *(uint4*)&mw[r][0] = *(const uint4*)pr;
      *(uint4*)&mw[r][4] = *(const uint4*)(pr + 4);
    }
  }

  // ---- energy: wave w covers k in [w*256, w*256+256) ----
  const u16* Qp = Qh + hoff + (size_t)(q0 + lr) * HDc + lh * 8;
  const u16* Qsp = Qsh + hoff + (size_t)(q0 + lr) * HDc + lh * 8;
  bf16x8 qf0 = *(const bf16x8*)Qp, qf1 = *(const bf16x8*)(Qp + 32);
  bf16x8 sf0 = *(const bf16x8*)Qsp, sf1 = *(const bf16x8*)(Qsp + 32);

#pragma unroll
  for (int kt = 0; kt < 16; ++kt) {
    int k0 = (w << 8) + (kt << 4);
    const u16* Kp = Kh + hoff + (size_t)(k0 + lr) * HDc + lh * 8;
    const u16* Ksp = Ksh + hoff + (size_t)(k0 + lr) * HDc + lh * 8;
    f32x4 e = {}, es = {};
    e = mfma16(qf0, *(const bf16x8*)Kp, e);
    e = mfma16(qf1, *(const bf16x8*)(Kp + 32), e);
    es = mfma16(sf0, *(const bf16x8*)Ksp, es);
    es = mfma16(sf1, *(const bf16x8*)(Ksp + 32), es);
    int col = k0 + lr;
#pragma unroll
    for (int r = 0; r < 4; ++r) {
      int row = lh * 4 + r;
      uint32_t mv = (mw[r][kt >> 1] >> (((kt & 1) << 4) + lr)) & 1u;
      E[(row << 10) + ((((col >> 3) ^ (row & 7)) << 3) | (col & 7))] =
          f2bf((mv ? es[r] : e[r]) * 0.125f);
    }
  }
  __syncthreads();

  // ---- softmax: wave w handles rows w*4 .. w*4+3; lane owns k=j*256+l*4 ----
  float* Pbase = Pout + ((size_t)bh * Sc + q0) * Sc;
#pragma unroll
  for (int rr = 0; rr < 4; ++rr) {
    int row = (w << 2) + rr;
    int sw = row & 7;
    float v[4][4];
#pragma unroll
    for (int jj = 0; jj < 4; ++jj) {
      int k = jj * 256 + (l << 2);
      ushort4 raw = *(const ushort4*)&E[(row << 10) + ((((k >> 3) ^ sw) << 3) | (k & 7))];
      v[jj][0] = bf2f(raw.x); v[jj][1] = bf2f(raw.y);
      v[jj][2] = bf2f(raw.z); v[jj][3] = bf2f(raw.w);
    }
    float m = -1e30f;
#pragma unroll
    for (int jj = 0; jj < 4; ++jj)
      m = fmaxf(m, fmaxf(fmaxf(v[jj][0], v[jj][1]), fmaxf(v[jj][2], v[jj][3])));
#pragma unroll
    for (int off = 32; off; off >>= 1) m = fmaxf(m, __shfl_xor(m, off));
    float s = 0.f;
#pragma unroll
    for (int jj = 0; jj < 4; ++jj)
#pragma unroll
      for (int i = 0; i < 4; ++i) { float tt = __expf(v[jj][i] - m); v[jj][i] = tt; s += tt; }
#pragma unroll
    for (int off = 32; off; off >>= 1) s += __shfl_xor(s, off);
    float inv = 1.f / s;
#pragma unroll
    for (int jj = 0; jj < 4; ++jj) {
      int k = jj * 256 + (l << 2);
      f32x4 pv = { v[jj][0] * inv, v[jj][1] * inv, v[jj][2] * inv, v[jj][3] * inv };
      *(f32x4*)(Pbase + (size_t)row * Sc + k) = pv;
      ushort4 wb;
      wb.x = f2bf(pv[0]); wb.y = f2bf(pv[1]); wb.z = f2bf(pv[2]); wb.w = f2bf(pv[3]);
      *(ushort4*)&E[(row << 10) + ((((k >> 3) ^ sw) << 3) | (k & 7))] = wb;
    }
  }
  __syncthreads();

  // ---- PV: wave w handles d-cols [w*16, w*16+16); A-frags straight from LDS ----
  const u16* Vb = Vth + ((size_t)bh * HDc + (w << 4) + lr) * Sc + lh * 8;
  const int swp = lr & 7;
  f32x4 acc0 = {}, acc1 = {};
#pragma unroll
  for (int k0 = 0; k0 < 1024; k0 += 64) {
    int ka = k0 + (lh << 3);
    bf16x8 a0 = *(const bf16x8*)&E[(lr << 10) + (((ka >> 3) ^ swp) << 3)];
    bf16x8 b0 = *(const bf16x8*)(Vb + k0);
    acc0 = mfma16(a0, b0, acc0);
    int kb = ka + 32;
    bf16x8 a1 = *(const bf16x8*)&E[(lr << 10) + (((kb >> 3) ^ swp) << 3)];
    bf16x8 b1 = *(const bf16x8*)(Vb + k0 + 32);
    acc1 = mfma16(a1, b1, acc1);
  }
  f32x4 acc = acc0 + acc1;
#pragma unroll
  for (int r = 0; r < 4; ++r) {
    int row = q0 + (lh << 2) + r;
    ctx[((size_t)b * Sc + row) * Hc + (h << 6) + (w << 4) + lr] = f2bf(acc[r]);
  }
}

extern "C" void kernel_launch(void* const* d_in, const int* in_sizes, int n_in,
                              void* d_out, int out_size, void* d_ws, size_t ws_size,
                              hipStream_t stream) {
  const float* fin[5] = { (const float*)d_in[0], (const float*)d_in[1], (const float*)d_in[2],
                          (const float*)d_in[3], (const float*)d_in[4] };
  const int* mask = (const int*)d_in[5];
  const float* W[6] = { (const float*)d_in[6], (const float*)d_in[8], (const float*)d_in[10],
                        (const float*)d_in[12], (const float*)d_in[14], (const float*)d_in[16] };
  const float* bias[6] = { (const float*)d_in[7], (const float*)d_in[9], (const float*)d_in[11],
                           (const float*)d_in[13], (const float*)d_in[15], (const float*)d_in[17] };

  float* out_x = (float*)d_out;
  float* out_attn = out_x + (size_t)Bc * Sc * Hc;

  const size_t NE = (size_t)Bc * Sc * Hc; // 4M elems
  const size_t NW = (size_t)Hc * Hc;      // 1M elems
  u16* p = (u16*)d_ws;
  u16* xin[5]; for (int i = 0; i < 5; ++i) { xin[i] = p; p += NE; }
  u16* wbf[6]; for (int i = 0; i < 6; ++i) { wbf[i] = p; p += NW; }
  u16* Qh  = p; p += NE;
  u16* Kh  = p; p += NE;
  u16* Qsh = p; p += NE;
  u16* Ksh = p; p += NE;
  u16* Vth = p; p += NE;
  u16* ctx = p; p += NE;
  uint32_t* mbits = (uint32_t*)xin[0]; // reused after proj5

  for (int i = 0; i < 5; ++i)
    cvt_kernel<<<(int)(NE / 8 / 256), 256, 0, stream>>>(fin[i], xin[i], (int)(NE / 8));
  for (int i = 0; i < 6; ++i)
    cvt_kernel<<<(int)(NW / 8 / 256), 256, 0, stream>>>(W[i], wbf[i], (int)(NW / 8));

  P5 args;
  u16* projout[5] = { Qh, Kh, Qsh, Ksh, Vth };
  for (int i = 0; i < 5; ++i) { args.A[i] = xin[i]; args.W[i] = wbf[i]; args.b[i] = bias[i]; args.o[i] = projout[i]; }
  proj5_kernel<<<dim3(Hc / 128, Mrows / 128, 5), 256, 0, stream>>>(args);

  maskpack_kernel<<<(int)((size_t)Bc * Sc * Sc / 32 / 256), 256, 0, stream>>>(mask, mbits);

  attn_kernel<<<dim3(Sc / 16, Bc * NHc), 256, 0, stream>>>(Qh, Kh, Qsh, Ksh, Vth, mbits, out_attn, ctx);

  gemmo_kernel<<<dim3(Hc / 128, Mrows / 128), 256, 0, stream>>>(ctx, wbf[5], bias[5], out_x);
}